// Round 22
// baseline (68.217 us; speedup 1.0000x reference)
//
#include <hip/hip_runtime.h>

typedef __bf16 bf16_t;
typedef __bf16 bf16x8 __attribute__((ext_vector_type(8)));
typedef __bf16 bf16x4 __attribute__((ext_vector_type(4)));
typedef float  f32x4  __attribute__((ext_vector_type(4)));
typedef float  f32x16 __attribute__((ext_vector_type(16)));
typedef char   i8x16  __attribute__((ext_vector_type(16)));
typedef char   i8x4   __attribute__((ext_vector_type(4)));
typedef int    i32x4  __attribute__((ext_vector_type(4)));

#define PIX 196      // 14*14
#define P_  12544    // 16*28*28
#define M_  512
#define SF  12.0f    // f quantization scale (|f| <~ 10)
#define SN  24.0f    // ny quantization scale (|ny| <~ 5.2)

__device__ inline void gload_lds16(const void* g, void* l) {
  __builtin_amdgcn_global_load_lds((const __attribute__((address_space(1))) void*)g,
                                   (__attribute__((address_space(3))) void*)l,
                                   16, 0, 0);
}

// ---- merged prep: [0,2560) nyprep | [2560,2816) wtb | [2816,3072) xt ----
__global__ __launch_bounds__(256) void k_prep(const float* __restrict__ conv_w,
                                              const float* __restrict__ x,
                                              const float* __restrict__ ny,
                                              const float* __restrict__ alpha,
                                              const float* __restrict__ sigma,
                                              bf16_t* __restrict__ wtb,
                                              bf16_t* __restrict__ xb,
                                              char* __restrict__ nys8,
                                              float* __restrict__ e_n) {
  __shared__ float xs[16][198];
  int bid = blockIdx.x, tid = threadIdx.x;
  if (bid < 2560) {
    // ---- ny -> i8 fragment-native 32-m chunks + e_n from QUANTIZED values ----
    int l = tid & 63;
    int row = bid * 4 + (tid >> 6);              // c*512+m, < 10240
    int c = row >> 9, m = row & 511;
    f32x4 v = *reinterpret_cast<const f32x4*>(ny + row * 256 + l * 4);
    i8x4 q8;
    float sq = 0.f;
#pragma unroll
    for (int i = 0; i < 4; ++i) {
      float fq = fminf(fmaxf(__builtin_rintf(v[i] * SN), -127.f), 127.f);
      q8[i] = (char)(int)fq;
      float fv = fq * (1.f / SN);
      sq += fv * fv;
    }
    int u = m >> 5, mf = (m >> 4) & 1, mc = m & 15;
    int ks = l >> 4, lg = (l >> 2) & 3, j0 = (l & 3) * 4;
    *reinterpret_cast<i8x4*>(nys8 + (c * 16 + u) * 8192 + mf * 4096 + ks * 1024 +
                             (lg * 16 + mc) * 16 + j0) = q8;
#pragma unroll
    for (int o = 1; o < 64; o <<= 1) sq += __shfl_xor(sq, o);
    if (l == 0) {
      float s = sigma[0];
      e_n[row] = __expf(-sq / (2.f * s * s)) * alpha[row];
    }
  } else if (bid < 2816) {
    // ---- conv_w [c][d][2][2] fp32 -> wtb bf16, fragment-native ----
    int c = bid - 2560, d = tid;
    f32x4 w = *reinterpret_cast<const f32x4*>(conv_w + (c * 256 + d) * 4);
    int ks = c >> 4, kb = (c >> 3) & 1, j = c & 7;
#pragma unroll
    for (int q = 0; q < 4; ++q) {
      int col = q * 256 + d;
      int cf = col >> 5;
      int lfrag = kb * 32 + (col & 31);
      wtb[((cf * 16 + ks) * 64 + lfrag) * 8 + j] = (bf16_t)w[q];
    }
  } else {
    // ---- x[n][c][hw] -> xb[p3][c] bf16, 16-c tile via LDS ----
    int idx2 = bid - 2816;
    int n = idx2 >> 4, c0 = (idx2 & 15) * 16;
    const float* xp = x + (n * 256 + c0) * PIX;
#pragma unroll
    for (int r = 0; r < 13; ++r) {
      int idx = r * 256 + tid;
      if (idx < 3136) xs[idx / PIX][idx % PIX] = xp[idx];
    }
    __syncthreads();
#pragma unroll
    for (int r = 0; r < 4; ++r) {
      int idx = r * 256 + tid;
      if (idx < 784) {
        int hw = idx >> 2, c4 = idx & 3;
        bf16x4 h;
#pragma unroll
        for (int i = 0; i < 4; ++i) h[i] = (bf16_t)xs[c4 * 4 + i][hw];
        *reinterpret_cast<bf16x4*>(xb + (n * PIX + hw) * 256 + c0 + c4 * 4) = h;
      }
    }
  }
}

// ---- conv as GEMM (bf16 MFMA), epilogue quantizes f -> i8 (verified R11/R15) ----
__global__ __launch_bounds__(256) void k_convT(const bf16_t* __restrict__ xb,
                                               const bf16_t* __restrict__ wtb,
                                               const float* __restrict__ conv_b,
                                               const float* __restrict__ mean,
                                               const float* __restrict__ mean_norm,
                                               char* __restrict__ fb8) {
  __shared__ bf16_t bs[32768];
  int rb = blockIdx.x * 64, cbase = blockIdx.y * 128;
  int tid = threadIdx.x, w = tid >> 6, l = tid & 63;
  int wr = w >> 1, wc = w & 1;
  const bf16_t* bsrc = wtb + blockIdx.y * 32768;
#pragma unroll
  for (int r = 0; r < 16; ++r) {
    int s = (r * 4 + w) * 64 + l;
    gload_lds16(bsrc + s * 8, bs + s * 8);
  }
  bf16x8 a[16];
  {
    const bf16_t* ap = xb + (rb + wr * 32 + (l & 31)) * 256 + (l >> 5) * 8;
#pragma unroll
    for (int ks = 0; ks < 16; ++ks) a[ks] = *reinterpret_cast<const bf16x8*>(ap + ks * 16);
  }
  __syncthreads();
  float scale = (20.f / mean_norm[0]) * SF;
  int hi = l >> 5;
#pragma unroll
  for (int cf = 0; cf < 2; ++cf) {
    f32x16 acc = {0.f,0.f,0.f,0.f,0.f,0.f,0.f,0.f,0.f,0.f,0.f,0.f,0.f,0.f,0.f,0.f};
#pragma unroll
    for (int ks = 0; ks < 16; ++ks) {
      bf16x8 b = *reinterpret_cast<const bf16x8*>(bs + ((wc * 2 + cf) * 16 + ks) * 512 + l * 8);
      acc = __builtin_amdgcn_mfma_f32_32x32x16_bf16(a[ks], b, acc, 0, 0, 0);
    }
    int col = cbase + wc * 64 + cf * 32 + (l & 31);
    int q = col >> 8, d = col & 255;
    float bias = conv_b[d], mn = mean[d];
    int qi = q >> 1, qj = q & 1;
#pragma unroll
    for (int r = 0; r < 16; ++r) {
      int p3 = rb + wr * 32 + (r & 3) + 8 * (r >> 2) + 4 * hi;
      int n = p3 / PIX, hw = p3 % PIX;
      int h = hw / 14, ww = hw % 14;
      int p = n * 784 + (2 * h + qi) * 28 + 2 * ww + qj;
      float v = fmaxf(acc[r] + bias, 0.f);
      float fq = fminf(fmaxf(__builtin_rintf((v - mn) * scale), -127.f), 127.f);
      fb8[p * 256 + d] = (char)(int)fq;
    }
  }
}

// ---- main: i8 16x16x64, TWO 32-m sub-chunks per barrier phase (15 barriers
// instead of 31); same registers/inner code as the verified R15/R21 loop ----
__global__ __launch_bounds__(256, 4) void k_falkon(const char* __restrict__ fb8,
                                                   const char* __restrict__ nys8,
                                                   const float* __restrict__ e_n,
                                                   const float* __restrict__ sigma,
                                                   float* __restrict__ out) {
  __shared__ char bs[2][16384];    // 2 x 16 KB ring (64-m phases = 2x32-m chunks)
  __shared__ float lds_en[512];
  int c = blockIdx.y, pb = blockIdx.x * 128;
  int tid = threadIdx.x, w = tid >> 6, l = tid & 63;

  if (c == 0 && tid < 128) {
    int p = pb + tid;
    out[(p / 784) * 16464 + (p % 784)] = -2.0f;
  }

  lds_en[tid] = e_n[c * M_ + tid];
  lds_en[256 + tid] = e_n[c * M_ + 256 + tid];

  // A frags: rf-tile row = pb + w*32 + rf*16 + (l&15); k = ks*64 + (l>>4)*16 + j
  i32x4 a[2][4];
  {
    const char* ap = fb8 + (pb + w * 32 + (l & 15)) * 256 + (l >> 4) * 16;
#pragma unroll
    for (int rf = 0; rf < 2; ++rf)
#pragma unroll
      for (int ks = 0; ks < 4; ++ks)
        a[rf][ks] = *reinterpret_cast<const i32x4*>(ap + rf * 16 * 256 + ks * 64);
  }

  float sg = sigma[0];
  float kl = 1.44269504088896340736f / (sg * sg);   // log2(e)/sigma^2
  float Ksc = kl * (1.f / (SF * SN));

  // fused e_f per rf from quantized frags (exact int sum of squares)
  float ef0, ef1;
#pragma unroll
  for (int rf = 0; rf < 2; ++rf) {
    int ssi = 0;
#pragma unroll
    for (int ks = 0; ks < 4; ++ks) {
      i8x16 q = __builtin_bit_cast(i8x16, a[rf][ks]);
#pragma unroll
      for (int j = 0; j < 16; ++j) {
        int qv = (signed char)q[j];
        ssi += qv * qv;
      }
    }
    ssi += __shfl_xor(ssi, 16);
    ssi += __shfl_xor(ssi, 32);
    float ef = __builtin_amdgcn_exp2f(-(float)ssi * (0.5f * kl / (SF * SF)));
    if (rf == 0) ef0 = ef; else ef1 = ef;
  }

  f32x4 sacc[2];
  sacc[0] = {0.f, 0.f, 0.f, 0.f};
  sacc[1] = {0.f, 0.f, 0.f, 0.f};

  const char* nb = nys8 + c * (16 * 8192);

  // stage one 16 KB phase (two consecutive 8 KB chunks): 4 x 16B per thread
  auto stage = [&](int u) {
    const char* src = nb + u * 16384;
    char* dst = &bs[u & 1][0];
#pragma unroll
    for (int r = 0; r < 4; ++r) {
      int slot = r * 256 + tid;
      gload_lds16(src + slot * 16, dst + slot * 16);
    }
  };

  // prologue: stage 0,1; vmcnt(4) => stage(0) landed (stage(1)'s 4 loads in flight)
  stage(0);
  stage(1);
  asm volatile("s_waitcnt vmcnt(4) lgkmcnt(0)" ::: "memory");
  __builtin_amdgcn_s_barrier();

  for (int u = 0; u < 8; ++u) {
#pragma unroll
    for (int h = 0; h < 2; ++h) {            // two 32-m sub-chunks, same regs
      const char* bp = &bs[u & 1][h * 8192] + l * 16;
      i32x4 b[2][4];
#pragma unroll
      for (int mf = 0; mf < 2; ++mf)
#pragma unroll
        for (int ks = 0; ks < 4; ++ks)
          b[mf][ks] = *reinterpret_cast<const i32x4*>(bp + mf * 4096 + ks * 1024);

      i32x4 acc[2][2];
#pragma unroll
      for (int rf = 0; rf < 2; ++rf)
#pragma unroll
        for (int mf = 0; mf < 2; ++mf) acc[rf][mf] = {0, 0, 0, 0};

      __builtin_amdgcn_s_setprio(1);
#pragma unroll
      for (int ks = 0; ks < 4; ++ks)
#pragma unroll
        for (int rf = 0; rf < 2; ++rf)
#pragma unroll
          for (int mf = 0; mf < 2; ++mf)
            acc[rf][mf] = __builtin_amdgcn_mfma_i32_16x16x64_i8(a[rf][ks], b[mf][ks],
                                                                acc[rf][mf], 0, 0, 0);
      __builtin_amdgcn_s_setprio(0);

      int u32 = u * 2 + h;                   // 32-m chunk index
      float en0 = lds_en[u32 * 32 + (l & 15)];
      float en1 = lds_en[u32 * 32 + 16 + (l & 15)];
#pragma unroll
      for (int rf = 0; rf < 2; ++rf)
#pragma unroll
        for (int r = 0; r < 4; ++r) {
          sacc[rf][r] += en0 * __builtin_amdgcn_exp2f((float)acc[rf][0][r] * Ksc)
                       + en1 * __builtin_amdgcn_exp2f((float)acc[rf][1][r] * Ksc);
        }
    }

    if (u < 7) {
      asm volatile("s_waitcnt lgkmcnt(0)" ::: "memory");
      __builtin_amdgcn_s_barrier();            // all waves done reading bs[u&1]
      if (u + 2 < 8) {
        stage(u + 2);
        asm volatile("s_waitcnt vmcnt(4)" ::: "memory");  // stage(u+1) landed
      } else {
        asm volatile("s_waitcnt vmcnt(0)" ::: "memory");  // tail: stage(7)
      }
      __builtin_amdgcn_s_barrier();            // bs[(u+1)&1] ready
    }
  }

  // reduce over 16 m-lanes; apply e_f via shfl; lanes with (l&15)==0 write
#pragma unroll
  for (int rf = 0; rf < 2; ++rf)
#pragma unroll
    for (int r = 0; r < 4; ++r) {
      float v = sacc[rf][r];
      v += __shfl_xor(v, 1);
      v += __shfl_xor(v, 2);
      v += __shfl_xor(v, 4);
      v += __shfl_xor(v, 8);
      int rr = (l >> 4) * 4 + r;               // 0..15 within rf tile
      float ef = __shfl(rf == 0 ? ef0 : ef1, rr);
      if ((l & 15) == 0) {
        int p = pb + w * 32 + rf * 16 + rr;
        out[(p / 784) * 16464 + (c + 1) * 784 + (p % 784)] = v * ef;
      }
    }
}

extern "C" void kernel_launch(void* const* d_in, const int* in_sizes, int n_in,
                              void* d_out, int out_size, void* d_ws, size_t ws_size,
                              hipStream_t stream) {
  const float* x         = (const float*)d_in[0];
  const float* conv_w    = (const float*)d_in[1];
  const float* conv_b    = (const float*)d_in[2];
  const float* mean      = (const float*)d_in[3];
  const float* mean_norm = (const float*)d_in[4];
  const float* ny        = (const float*)d_in[5];
  const float* alpha     = (const float*)d_in[6];
  const float* sigma     = (const float*)d_in[7];
  float* out = (float*)d_out;

  char* ws = (char*)d_ws;
  bf16_t* wtb  = (bf16_t*)ws;                   //   524,288 B
  bf16_t* xb   = (bf16_t*)(ws + 524288);        // 1,605,632 B
  char*   fb8  = (char*)(ws + 2129920);         // 3,211,264 B
  char*   nys8 = (char*)(ws + 5341184);         // 2,621,440 B
  float*  e_n  = (float*)(ws + 7962624);        //    40,960 B

  k_prep<<<dim3(3072), dim3(256), 0, stream>>>(conv_w, x, ny, alpha, sigma,
                                               wtb, xb, nys8, e_n);
  k_convT<<<dim3(49, 8), dim3(256), 0, stream>>>(xb, wtb, conv_b, mean, mean_norm, fb8);
  k_falkon<<<dim3(98, 20), dim3(256), 0, stream>>>(fb8, nys8, e_n, sigma, out);
}

// Round 23
// 66.143 us; speedup vs baseline: 1.0314x; 1.0314x over previous
//
#include <hip/hip_runtime.h>

typedef __bf16 bf16_t;
typedef __bf16 bf16x8 __attribute__((ext_vector_type(8)));
typedef __bf16 bf16x4 __attribute__((ext_vector_type(4)));
typedef float  f32x4  __attribute__((ext_vector_type(4)));
typedef float  f32x16 __attribute__((ext_vector_type(16)));
typedef char   i8x16  __attribute__((ext_vector_type(16)));
typedef char   i8x4   __attribute__((ext_vector_type(4)));
typedef int    i32x4  __attribute__((ext_vector_type(4)));

#define PIX 196      // 14*14
#define P_  12544    // 16*28*28
#define M_  512
#define SF  12.0f    // f quantization scale (|f| <~ 10)
#define SN  24.0f    // ny quantization scale (|ny| <~ 5.2)

__device__ inline void gload_lds16(const void* g, void* l) {
  __builtin_amdgcn_global_load_lds((const __attribute__((address_space(1))) void*)g,
                                   (__attribute__((address_space(3))) void*)l,
                                   16, 0, 0);
}

// ---- merged prep: [0,2560) nyprep | [2560,2816) wtb | [2816,3072) xt ----
__global__ __launch_bounds__(256) void k_prep(const float* __restrict__ conv_w,
                                              const float* __restrict__ x,
                                              const float* __restrict__ ny,
                                              const float* __restrict__ alpha,
                                              const float* __restrict__ sigma,
                                              bf16_t* __restrict__ wtb,
                                              bf16_t* __restrict__ xb,
                                              char* __restrict__ nys8,
                                              float* __restrict__ e_n) {
  __shared__ float xs[16][198];
  int bid = blockIdx.x, tid = threadIdx.x;
  if (bid < 2560) {
    // ---- ny -> i8 fragment-native 32-m chunks + e_n from QUANTIZED values ----
    int l = tid & 63;
    int row = bid * 4 + (tid >> 6);              // c*512+m, < 10240
    int c = row >> 9, m = row & 511;
    f32x4 v = *reinterpret_cast<const f32x4*>(ny + row * 256 + l * 4);
    i8x4 q8;
    float sq = 0.f;
#pragma unroll
    for (int i = 0; i < 4; ++i) {
      float fq = fminf(fmaxf(__builtin_rintf(v[i] * SN), -127.f), 127.f);
      q8[i] = (char)(int)fq;
      float fv = fq * (1.f / SN);
      sq += fv * fv;
    }
    int u = m >> 5, mf = (m >> 4) & 1, mc = m & 15;
    int ks = l >> 4, lg = (l >> 2) & 3, j0 = (l & 3) * 4;
    *reinterpret_cast<i8x4*>(nys8 + (c * 16 + u) * 8192 + mf * 4096 + ks * 1024 +
                             (lg * 16 + mc) * 16 + j0) = q8;
#pragma unroll
    for (int o = 1; o < 64; o <<= 1) sq += __shfl_xor(sq, o);
    if (l == 0) {
      float s = sigma[0];
      e_n[row] = __expf(-sq / (2.f * s * s)) * alpha[row];
    }
  } else if (bid < 2816) {
    // ---- conv_w [c][d][2][2] fp32 -> wtb bf16, fragment-native ----
    int c = bid - 2560, d = tid;
    f32x4 w = *reinterpret_cast<const f32x4*>(conv_w + (c * 256 + d) * 4);
    int ks = c >> 4, kb = (c >> 3) & 1, j = c & 7;
#pragma unroll
    for (int q = 0; q < 4; ++q) {
      int col = q * 256 + d;
      int cf = col >> 5;
      int lfrag = kb * 32 + (col & 31);
      wtb[((cf * 16 + ks) * 64 + lfrag) * 8 + j] = (bf16_t)w[q];
    }
  } else {
    // ---- x[n][c][hw] -> xb[p3][c] bf16, 16-c tile via LDS ----
    int idx2 = bid - 2816;
    int n = idx2 >> 4, c0 = (idx2 & 15) * 16;
    const float* xp = x + (n * 256 + c0) * PIX;
#pragma unroll
    for (int r = 0; r < 13; ++r) {
      int idx = r * 256 + tid;
      if (idx < 3136) xs[idx / PIX][idx % PIX] = xp[idx];
    }
    __syncthreads();
#pragma unroll
    for (int r = 0; r < 4; ++r) {
      int idx = r * 256 + tid;
      if (idx < 784) {
        int hw = idx >> 2, c4 = idx & 3;
        bf16x4 h;
#pragma unroll
        for (int i = 0; i < 4; ++i) h[i] = (bf16_t)xs[c4 * 4 + i][hw];
        *reinterpret_cast<bf16x4*>(xb + (n * PIX + hw) * 256 + c0 + c4 * 4) = h;
      }
    }
  }
}

// ---- conv as GEMM (bf16 MFMA), epilogue quantizes f -> i8 (verified R11/R15) ----
__global__ __launch_bounds__(256) void k_convT(const bf16_t* __restrict__ xb,
                                               const bf16_t* __restrict__ wtb,
                                               const float* __restrict__ conv_b,
                                               const float* __restrict__ mean,
                                               const float* __restrict__ mean_norm,
                                               char* __restrict__ fb8) {
  __shared__ bf16_t bs[32768];
  int rb = blockIdx.x * 64, cbase = blockIdx.y * 128;
  int tid = threadIdx.x, w = tid >> 6, l = tid & 63;
  int wr = w >> 1, wc = w & 1;
  const bf16_t* bsrc = wtb + blockIdx.y * 32768;
#pragma unroll
  for (int r = 0; r < 16; ++r) {
    int s = (r * 4 + w) * 64 + l;
    gload_lds16(bsrc + s * 8, bs + s * 8);
  }
  bf16x8 a[16];
  {
    const bf16_t* ap = xb + (rb + wr * 32 + (l & 31)) * 256 + (l >> 5) * 8;
#pragma unroll
    for (int ks = 0; ks < 16; ++ks) a[ks] = *reinterpret_cast<const bf16x8*>(ap + ks * 16);
  }
  __syncthreads();
  float scale = (20.f / mean_norm[0]) * SF;
  int hi = l >> 5;
#pragma unroll
  for (int cf = 0; cf < 2; ++cf) {
    f32x16 acc = {0.f,0.f,0.f,0.f,0.f,0.f,0.f,0.f,0.f,0.f,0.f,0.f,0.f,0.f,0.f,0.f};
#pragma unroll
    for (int ks = 0; ks < 16; ++ks) {
      bf16x8 b = *reinterpret_cast<const bf16x8*>(bs + ((wc * 2 + cf) * 16 + ks) * 512 + l * 8);
      acc = __builtin_amdgcn_mfma_f32_32x32x16_bf16(a[ks], b, acc, 0, 0, 0);
    }
    int col = cbase + wc * 64 + cf * 32 + (l & 31);
    int q = col >> 8, d = col & 255;
    float bias = conv_b[d], mn = mean[d];
    int qi = q >> 1, qj = q & 1;
#pragma unroll
    for (int r = 0; r < 16; ++r) {
      int p3 = rb + wr * 32 + (r & 3) + 8 * (r >> 2) + 4 * hi;
      int n = p3 / PIX, hw = p3 % PIX;
      int h = hw / 14, ww = hw % 14;
      int p = n * 784 + (2 * h + qi) * 28 + 2 * ww + qj;
      float v = fmaxf(acc[r] + bias, 0.f);
      float fq = fminf(fmaxf(__builtin_rintf((v - mn) * scale), -127.f), 127.f);
      fb8[p * 256 + d] = (char)(int)fq;
    }
  }
}

// ---- main: i8 16x16x64, 32 rows/wave, 32-m chunks, R8 skeleton, 4 blocks/CU ----
__global__ __launch_bounds__(256, 4) void k_falkon(const char* __restrict__ fb8,
                                                   const char* __restrict__ nys8,
                                                   const float* __restrict__ e_n,
                                                   const float* __restrict__ sigma,
                                                   float* __restrict__ out) {
  __shared__ char bs[2][8192];     // 2 x 8 KB ring (32-m chunks)
  __shared__ float lds_en[512];
  int c = blockIdx.y, pb = blockIdx.x * 128;
  int tid = threadIdx.x, w = tid >> 6, l = tid & 63;

  if (c == 0 && tid < 128) {
    int p = pb + tid;
    out[(p / 784) * 16464 + (p % 784)] = -2.0f;
  }

  lds_en[tid] = e_n[c * M_ + tid];
  lds_en[256 + tid] = e_n[c * M_ + 256 + tid];

  // A frags: rf-tile row = pb + w*32 + rf*16 + (l&15); k = ks*64 + (l>>4)*16 + j
  i32x4 a[2][4];
  {
    const char* ap = fb8 + (pb + w * 32 + (l & 15)) * 256 + (l >> 4) * 16;
#pragma unroll
    for (int rf = 0; rf < 2; ++rf)
#pragma unroll
      for (int ks = 0; ks < 4; ++ks)
        a[rf][ks] = *reinterpret_cast<const i32x4*>(ap + rf * 16 * 256 + ks * 64);
  }

  float sg = sigma[0];
  float kl = 1.44269504088896340736f / (sg * sg);   // log2(e)/sigma^2
  float Ksc = kl * (1.f / (SF * SN));

  // fused e_f per rf from quantized frags (exact int sum of squares)
  float ef0, ef1;
#pragma unroll
  for (int rf = 0; rf < 2; ++rf) {
    int ssi = 0;
#pragma unroll
    for (int ks = 0; ks < 4; ++ks) {
      i8x16 q = __builtin_bit_cast(i8x16, a[rf][ks]);
#pragma unroll
      for (int j = 0; j < 16; ++j) {
        int qv = (signed char)q[j];
        ssi += qv * qv;
      }
    }
    ssi += __shfl_xor(ssi, 16);
    ssi += __shfl_xor(ssi, 32);
    float ef = __builtin_amdgcn_exp2f(-(float)ssi * (0.5f * kl / (SF * SF)));
    if (rf == 0) ef0 = ef; else ef1 = ef;
  }

  f32x4 sacc[2];
  sacc[0] = {0.f, 0.f, 0.f, 0.f};
  sacc[1] = {0.f, 0.f, 0.f, 0.f};

  const char* nb = nys8 + c * (16 * 8192);

  auto stage = [&](int u) {
    const char* src = nb + u * 8192;
    char* dst = &bs[u & 1][0];
#pragma unroll
    for (int r = 0; r < 2; ++r) {
      int slot = r * 256 + tid;
      gload_lds16(src + slot * 16, dst + slot * 16);
    }
  };

  // prologue: stage 0,1; vmcnt(2) => stage(0) landed (stage(1)'s 2 loads in flight)
  stage(0);
  stage(1);
  asm volatile("s_waitcnt vmcnt(2) lgkmcnt(0)" ::: "memory");
  __builtin_amdgcn_s_barrier();

  for (int u = 0; u < 16; ++u) {
    const char* bp = &bs[u & 1][0] + l * 16;
    i32x4 b[2][4];
#pragma unroll
    for (int mf = 0; mf < 2; ++mf)
#pragma unroll
      for (int ks = 0; ks < 4; ++ks)
        b[mf][ks] = *reinterpret_cast<const i32x4*>(bp + mf * 4096 + ks * 1024);

    i32x4 acc[2][2];
#pragma unroll
    for (int rf = 0; rf < 2; ++rf)
#pragma unroll
      for (int mf = 0; mf < 2; ++mf) acc[rf][mf] = {0, 0, 0, 0};

    __builtin_amdgcn_s_setprio(1);
#pragma unroll
    for (int ks = 0; ks < 4; ++ks)
#pragma unroll
      for (int rf = 0; rf < 2; ++rf)
#pragma unroll
        for (int mf = 0; mf < 2; ++mf)
          acc[rf][mf] = __builtin_amdgcn_mfma_i32_16x16x64_i8(a[rf][ks], b[mf][ks],
                                                              acc[rf][mf], 0, 0, 0);
    __builtin_amdgcn_s_setprio(0);

    float en0 = lds_en[u * 32 + (l & 15)];
    float en1 = lds_en[u * 32 + 16 + (l & 15)];
#pragma unroll
    for (int rf = 0; rf < 2; ++rf)
#pragma unroll
      for (int r = 0; r < 4; ++r) {
        sacc[rf][r] += en0 * __builtin_amdgcn_exp2f((float)acc[rf][0][r] * Ksc)
                     + en1 * __builtin_amdgcn_exp2f((float)acc[rf][1][r] * Ksc);
      }

    if (u < 15) {
      asm volatile("s_waitcnt lgkmcnt(0)" ::: "memory");
      __builtin_amdgcn_s_barrier();            // all waves done reading bs[u&1]
      if (u + 2 < 16) {
        stage(u + 2);
        asm volatile("s_waitcnt vmcnt(2)" ::: "memory");  // stage(u+1) landed
      } else {
        asm volatile("s_waitcnt vmcnt(0)" ::: "memory");  // tail: stage(15)
      }
      __builtin_amdgcn_s_barrier();            // bs[(u+1)&1] ready
    }
  }

  // reduce over 16 m-lanes; apply e_f via shfl; lanes with (l&15)==0 write
#pragma unroll
  for (int rf = 0; rf < 2; ++rf)
#pragma unroll
    for (int r = 0; r < 4; ++r) {
      float v = sacc[rf][r];
      v += __shfl_xor(v, 1);
      v += __shfl_xor(v, 2);
      v += __shfl_xor(v, 4);
      v += __shfl_xor(v, 8);
      int rr = (l >> 4) * 4 + r;               // 0..15 within rf tile
      float ef = __shfl(rf == 0 ? ef0 : ef1, rr);
      if ((l & 15) == 0) {
        int p = pb + w * 32 + rf * 16 + rr;
        out[(p / 784) * 16464 + (c + 1) * 784 + (p % 784)] = v * ef;
      }
    }
}

extern "C" void kernel_launch(void* const* d_in, const int* in_sizes, int n_in,
                              void* d_out, int out_size, void* d_ws, size_t ws_size,
                              hipStream_t stream) {
  const float* x         = (const float*)d_in[0];
  const float* conv_w    = (const float*)d_in[1];
  const float* conv_b    = (const float*)d_in[2];
  const float* mean      = (const float*)d_in[3];
  const float* mean_norm = (const float*)d_in[4];
  const float* ny        = (const float*)d_in[5];
  const float* alpha     = (const float*)d_in[6];
  const float* sigma     = (const float*)d_in[7];
  float* out = (float*)d_out;

  char* ws = (char*)d_ws;
  bf16_t* wtb  = (bf16_t*)ws;                   //   524,288 B
  bf16_t* xb   = (bf16_t*)(ws + 524288);        // 1,605,632 B
  char*   fb8  = (char*)(ws + 2129920);         // 3,211,264 B
  char*   nys8 = (char*)(ws + 5341184);         // 2,621,440 B
  float*  e_n  = (float*)(ws + 7962624);        //    40,960 B

  k_prep<<<dim3(3072), dim3(256), 0, stream>>>(conv_w, x, ny, alpha, sigma,
                                               wtb, xb, nys8, e_n);
  k_convT<<<dim3(49, 8), dim3(256), 0, stream>>>(xb, wtb, conv_b, mean, mean_norm, fb8);
  k_falkon<<<dim3(98, 20), dim3(256), 0, stream>>>(fb8, nys8, e_n, sigma, out);
}